// Round 2
// baseline (2006.787 us; speedup 1.0000x reference)
//
#include <hip/hip_runtime.h>
#include <hip/hip_bf16.h>
#include <stdint.h>

typedef unsigned short ushort_t;
typedef __attribute__((ext_vector_type(8))) short bf16x8;
typedef __attribute__((ext_vector_type(4))) float f32x4;

#define T_DIM 128
#define N_DIM 256
#define H_DIM 512
#define G3    1536
#define K2DIM 544   // 520 padded to multiple of 32

// ---- ws layout (bytes) ----
#define OFF_X2    0L
#define SZ_X2     (32768L*K2DIM*2)                       // 35,651,584
#define OFF_W2    (OFF_X2 + SZ_X2)
#define SZ_W2     (1536L*K2DIM*2)
#define OFF_WHH   (OFF_W2 + SZ_W2)
#define SZ_WHH    (1536L*512*2)
#define OFF_WHHP  (OFF_WHH + SZ_WHH)
#define OFF_GI    (OFF_WHHP + SZ_WHH)
#define SZ_GI     (32768L*1536*2)                        // 100,663,296
#define OFF_HBUF  (OFF_GI + SZ_GI)
#define SZ_HBUF   (4L*N_DIM*H_DIM*2)                     // [cell][parity][n*512+k]
#define OFF_FLAGS (OFF_HBUF + SZ_HBUF)
#define SZ_FLAGS  (8L*128*4)

// output offsets (floats)
#define OUT_OUTS   0L
#define OUT_HXS    16777216L
#define OUT_OUTSP  16908288L
#define OUT_HYS    33685504L

__device__ __forceinline__ ushort_t f2bf(float f) {
    union { float f; unsigned u; } v; v.f = f;
    unsigned u = v.u;
    u += 0x7fffu + ((u >> 16) & 1u);   // RNE
    return (ushort_t)(u >> 16);
}
__device__ __forceinline__ float bf2f(ushort_t u) {
    union { unsigned u; float f; } v; v.u = ((unsigned)u) << 16;
    return v.f;
}
__device__ __forceinline__ float sigm(float x) { return 1.f / (1.f + __expf(-x)); }

// ============================ K1: prep ============================
__global__ __launch_bounds__(256) void prep_kernel(
    const float* __restrict__ x, const float* __restrict__ hxs, const float* __restrict__ hys,
    const float* __restrict__ gru_init, const float* __restrict__ masks, const float* __restrict__ at,
    const float* __restrict__ w_ih, const float* __restrict__ w_hh,
    const float* __restrict__ w_ih_p, const float* __restrict__ w_hh_p,
    ushort_t* __restrict__ x2, ushort_t* __restrict__ W2,
    ushort_t* __restrict__ whh, ushort_t* __restrict__ whhp,
    ushort_t* __restrict__ hbuf, int* __restrict__ flags)
{
    const long n_x2   = 32768L * K2DIM;
    const long n_W2   = 1536L * K2DIM;
    const long n_whh  = 1536L * 512;
    const long n_h    = 256L * 512;
    const long total  = n_x2 + n_W2 + 2*n_whh + 2*n_h + 8*128;
    for (long i = (long)blockIdx.x * blockDim.x + threadIdx.x; i < total;
         i += (long)gridDim.x * blockDim.x) {
        long j = i;
        if (j < n_x2) {   // x2 = [x | at*mask | 0pad] bf16
            int r = (int)(j / K2DIM), c = (int)(j % K2DIM);
            float v;
            if (c < 512)       v = x[(long)r*512 + c];
            else if (c < 520)  v = at[(long)r*8 + (c - 512)] * masks[r];
            else               v = 0.f;
            x2[j] = f2bf(v); continue;
        }
        j -= n_x2;
        if (j < n_W2) {   // W2 = w_ih padded to 544 cols
            int r = (int)(j / K2DIM), c = (int)(j % K2DIM);
            W2[j] = f2bf(c < 520 ? w_ih[(long)r*520 + c] : 0.f); continue;
        }
        j -= n_W2;
        if (j < n_whh) { whh[j]  = f2bf(w_hh[j]);   continue; }
        j -= n_whh;
        if (j < n_whh) { whhp[j] = f2bf(w_hh_p[j]); continue; }
        j -= n_whh;
        if (j < n_h) {    // hbuf cell0 parity0: hxs * m0
            int n = (int)(j >> 9); float m = masks[n];
            hbuf[j] = f2bf(hxs[j] * m); continue;
        }
        j -= n_h;
        if (j < n_h) {    // hbuf cell1 parity0: hys*m0 + g0*(1-m0)
            int n = (int)(j >> 9); float m = masks[n];
            hbuf[2*131072 + j] = f2bf(hys[j] * m + gru_init[j] * (1.f - m)); continue;
        }
        j -= n_h;
        flags[j] = 0;
    }
}

// ============================ K2: GI GEMM ============================
// GI(32768 x 1536) bf16 = x2(32768 x 544) @ W2(1536 x 544)^T   (no bias)
__global__ __launch_bounds__(256) void gi_gemm(
    const ushort_t* __restrict__ x2, const ushort_t* __restrict__ W2, ushort_t* __restrict__ GI)
{
    __shared__ ushort_t As2[128 * 40];   // 32 + 8 pad (stride 80B: 2-way conflict = free)
    __shared__ ushort_t Bs2[128 * 40];
    const int bid = blockIdx.x;
    const int m0 = (bid & 255) * 128;
    const int j0 = (bid >> 8) * 128;
    const int w = threadIdx.x >> 6, l = threadIdx.x & 63;
    const int lrow = l & 15, lq = l >> 4;
    const int wm = (w & 1) * 64, wn = (w >> 1) * 64;
    const int srow = threadIdx.x >> 1, shalf = threadIdx.x & 1;

    f32x4 acc[4][4] = {};
    for (int k0 = 0; k0 < K2DIM; k0 += 32) {
        __syncthreads();
        {
            const ushort_t* sa = x2 + (long)(m0 + srow) * K2DIM + k0 + shalf * 16;
            *(uint4*)(As2 + srow*40 + shalf*16)     = *(const uint4*)(sa);
            *(uint4*)(As2 + srow*40 + shalf*16 + 8) = *(const uint4*)(sa + 8);
            const ushort_t* sb = W2 + (long)(j0 + srow) * K2DIM + k0 + shalf * 16;
            *(uint4*)(Bs2 + srow*40 + shalf*16)     = *(const uint4*)(sb);
            *(uint4*)(Bs2 + srow*40 + shalf*16 + 8) = *(const uint4*)(sb + 8);
        }
        __syncthreads();
        bf16x8 a[4], b[4];
#pragma unroll
        for (int i = 0; i < 4; ++i) a[i] = *(const bf16x8*)(As2 + (wm + i*16 + lrow)*40 + lq*8);
#pragma unroll
        for (int jj = 0; jj < 4; ++jj) b[jj] = *(const bf16x8*)(Bs2 + (wn + jj*16 + lrow)*40 + lq*8);
#pragma unroll
        for (int i = 0; i < 4; ++i)
#pragma unroll
            for (int jj = 0; jj < 4; ++jj)
                acc[i][jj] = __builtin_amdgcn_mfma_f32_16x16x32_bf16(a[i], b[jj], acc[i][jj], 0, 0, 0);
    }
#pragma unroll
    for (int i = 0; i < 4; ++i) {
        int mrow_b = m0 + wm + i*16 + lq*4;
#pragma unroll
        for (int jj = 0; jj < 4; ++jj) {
            int coln = j0 + wn + jj*16 + lrow;
#pragma unroll
            for (int reg = 0; reg < 4; ++reg)
                GI[(long)(mrow_b + reg) * G3 + coln] = f2bf(acc[i][jj][reg]);
        }
    }
}

// ============================ K3: persistent recurrent ============================
// 256 blocks x 256 threads, 1 block/CU. Block: cell (hx/hy) x rowgroup(64 rows) x colgroup(16 h-cols).
// Group = blockIdx&7 (cell,rg) -> 32 col-blocks sync via per-(group,step) flags.
__global__ __launch_bounds__(256) void recurrent_kernel(
    float* __restrict__ d_out,
    const ushort_t* __restrict__ GI,
    const ushort_t* __restrict__ whh, const ushort_t* __restrict__ whhp,
    ushort_t* __restrict__ hbuf, int* __restrict__ flags,
    const float* __restrict__ masks, const float* __restrict__ gru_init,
    const float* __restrict__ at, const float* __restrict__ w_ih_p,
    const float* __restrict__ b_ih, const float* __restrict__ b_hh,
    const float* __restrict__ b_ih_p, const float* __restrict__ b_hh_p)
{
    extern __shared__ char smem_raw[];
    ushort_t* Ws = (ushort_t*)smem_raw;          // 48 x 520  (49,920 B)
    ushort_t* As = Ws + 48 * 520;                // 64 x 520  (66,560 B)
    float*    Wa = (float*)(As + 64 * 520);      // 48 x 8    (1,536 B)
    float*    maL = Wa + 48 * 8;                 // 64 x 8    (2,048 B)

    const int bid = blockIdx.x;
    const int g    = bid & 7;
    const int cell = g & 1;
    const int rg   = g >> 1;
    const int cg   = bid >> 3;
    const int rows0 = rg * 64;
    const int hcol0 = cg * 16;
    const int tid = threadIdx.x;
    const int w = tid >> 6, l = tid & 63;
    const int lrow = l & 15, lq = l >> 4;

    // ---- prologue: W tile into LDS (once, reused all 128 steps) ----
    {
        const ushort_t* Wg = cell ? whhp : whh;
#pragma unroll
        for (int it = 0; it < 12; ++it) {
            int c = it * 256 + tid;            // 0..3071 : 48 rows x 64 x 16B
            int gl = c >> 6, kc = c & 63;
            int grow = (gl >> 4) * 512 + hcol0 + (gl & 15);
            *(uint4*)(Ws + gl*520 + kc*8) = *(const uint4*)(Wg + (long)grow*512 + kc*8);
        }
        if (cell == 1) {                       // action weights (48 x 8 f32) -- 384 floats, 256 threads
            for (int i = tid; i < 384; i += 256) {
                int gl = i >> 3, k = i & 7;
                int grow = (gl >> 4) * 512 + hcol0 + (gl & 15);
                Wa[i] = w_ih_p[(long)grow*8 + k];
            }
        }
    }
    // per-lane biases (col fixed for whole kernel)
    const int col = hcol0 + lrow;
    const float* bi = cell ? b_ih_p : b_ih;
    const float* bh = cell ? b_hh_p : b_hh;
    const float bihr = bi[col], bihz = bi[512 + col], bihn = bi[1024 + col];
    const float bhhr = bh[col], bhhz = bh[512 + col], bhhn = bh[1024 + col];
    __syncthreads();

    const int arow_off = (w * 16 + lrow) * 520 + lq * 8;
    const int brow0 = lrow * 520 + lq * 8;

#pragma unroll 1
    for (int t = 0; t < T_DIM; ++t) {
        // ---- wait for step-t input (written by step t-1 producers of this group) ----
        if (t > 0) {
            if (tid == 0) {
                int* fl = &flags[g * 128 + t];
                int spins = 0;
                while (__hip_atomic_load(fl, __ATOMIC_RELAXED, __HIP_MEMORY_SCOPE_AGENT) < 32) {
                    if (++spins > (1 << 20)) break;   // safety: fail loud, not hung
                    __builtin_amdgcn_s_sleep(1);
                }
                (void)__hip_atomic_load(fl, __ATOMIC_ACQUIRE, __HIP_MEMORY_SCOPE_AGENT);
            }
            __syncthreads();
        }
        // ---- stage A = h~ tile (64 x 512 bf16, pre-masked) ----
        const ushort_t* hsrc = hbuf + ((cell * 2 + (t & 1)) * 131072);
#pragma unroll
        for (int it = 0; it < 16; ++it) {
            int c = it * 256 + tid;            // 64 rows x 64 x 16B
            int row = c >> 6, kc = c & 63;
            *(uint4*)(As + row*520 + kc*8) = *(const uint4*)(hsrc + ((rows0 + row) << 9) + kc*8);
        }
        if (cell == 1 && tid < 128) {          // ma = at[t]*m[t]  (64 x 8 f32)
            int row = tid >> 1, part = tid & 1;
            int nabs = rows0 + row;
            const float4 av = *(const float4*)(at + ((long)t*256 + nabs)*8 + part*4);
            float m = masks[t*256 + nabs];
            float4 r; r.x = av.x*m; r.y = av.y*m; r.z = av.z*m; r.w = av.w*m;
            *(float4*)(maL + row*8 + part*4) = r;
        }
        __syncthreads();

        // ---- MFMA: 16 rows x 48 gate-cols per wave, K=512 ----
        f32x4 accR = {0.f,0.f,0.f,0.f}, accZ = {0.f,0.f,0.f,0.f}, accN = {0.f,0.f,0.f,0.f};
#pragma unroll
        for (int ks = 0; ks < 16; ++ks) {
            bf16x8 a  = *(const bf16x8*)(As + arow_off + ks*32);
            bf16x8 br = *(const bf16x8*)(Ws + brow0 + ks*32);
            bf16x8 bz = *(const bf16x8*)(Ws + brow0 + 16*520 + ks*32);
            bf16x8 bn = *(const bf16x8*)(Ws + brow0 + 32*520 + ks*32);
            accR = __builtin_amdgcn_mfma_f32_16x16x32_bf16(a, br, accR, 0, 0, 0);
            accZ = __builtin_amdgcn_mfma_f32_16x16x32_bf16(a, bz, accZ, 0, 0, 0);
            accN = __builtin_amdgcn_mfma_f32_16x16x32_bf16(a, bn, accN, 0, 0, 0);
        }

        // ---- epilogue: GRU gate math + stores ----
        float* outBase = d_out + (cell ? OUT_OUTSP : OUT_OUTS);
#pragma unroll
        for (int reg = 0; reg < 4; ++reg) {
            int nloc = w * 16 + lq * 4 + reg;
            int nabs = rows0 + nloc;
            long row_tn = (long)t * 256 + nabs;
            float ghr = accR[reg], ghz = accZ[reg], ghn = accN[reg];
            float gir, giz, gin;
            if (cell == 0) {
                const ushort_t* gi = GI + row_tn * G3;
                gir = bf2f(gi[col]); giz = bf2f(gi[512 + col]); gin = bf2f(gi[1024 + col]);
            } else {
                const float* mrow = maL + nloc * 8;
                const float* war = Wa + lrow * 8;
                const float* waz = Wa + (16 + lrow) * 8;
                const float* wan = Wa + (32 + lrow) * 8;
                gir = 0.f; giz = 0.f; gin = 0.f;
#pragma unroll
                for (int k = 0; k < 8; ++k) {
                    float m = mrow[k];
                    gir += m * war[k]; giz += m * waz[k]; gin += m * wan[k];
                }
            }
            float r = sigm(gir + bihr + ghr + bhhr);
            float z = sigm(giz + bihz + ghz + bhhz);
            float n = tanhf(gin + bihn + r * (ghn + bhhn));
            float htil = bf2f(As[nloc * 520 + col]);   // masked h that entered the GEMM
            float hnew = (1.f - z) * n + z * htil;

            outBase[row_tn * 512 + col] = hnew;
            if (t == T_DIM - 1) {
                float* fin = d_out + (cell ? OUT_HYS : OUT_HXS);
                fin[(long)nabs * 512 + col] = hnew;
            } else {
                float mn = masks[(t + 1) * 256 + nabs];
                float hn;
                if (cell == 0) hn = hnew * mn;
                else           hn = hnew * mn + gru_init[((long)(t + 1) * 256 + nabs) * 512 + col] * (1.f - mn);
                hbuf[((cell * 2 + ((t + 1) & 1)) * 131072) + nabs * 512 + col] = f2bf(hn);
            }
        }
        __syncthreads();   // drains vmcnt for all waves -> all h~ stores complete
        if (t < T_DIM - 1 && tid == 0)
            __hip_atomic_fetch_add(&flags[g * 128 + (t + 1)], 1, __ATOMIC_RELEASE, __HIP_MEMORY_SCOPE_AGENT);
    }
}

// ============================ launcher ============================
extern "C" void kernel_launch(void* const* d_in, const int* in_sizes, int n_in,
                              void* d_out, int out_size, void* d_ws, size_t ws_size,
                              hipStream_t stream) {
    const float* x        = (const float*)d_in[0];
    const float* hxs      = (const float*)d_in[1];
    const float* hys      = (const float*)d_in[2];
    const float* gru_init = (const float*)d_in[3];
    const float* masks    = (const float*)d_in[4];
    const float* at       = (const float*)d_in[5];
    const float* w_ih     = (const float*)d_in[6];
    const float* w_hh     = (const float*)d_in[7];
    const float* b_ih     = (const float*)d_in[8];
    const float* b_hh     = (const float*)d_in[9];
    const float* w_ih_p   = (const float*)d_in[10];
    const float* w_hh_p   = (const float*)d_in[11];
    const float* b_ih_p   = (const float*)d_in[12];
    const float* b_hh_p   = (const float*)d_in[13];
    float* out = (float*)d_out;

    char* ws = (char*)d_ws;
    ushort_t* x2    = (ushort_t*)(ws + OFF_X2);
    ushort_t* W2    = (ushort_t*)(ws + OFF_W2);
    ushort_t* whh   = (ushort_t*)(ws + OFF_WHH);
    ushort_t* whhp  = (ushort_t*)(ws + OFF_WHHP);
    ushort_t* GI    = (ushort_t*)(ws + OFF_GI);
    ushort_t* hbuf  = (ushort_t*)(ws + OFF_HBUF);
    int*      flags = (int*)(ws + OFF_FLAGS);

    prep_kernel<<<2048, 256, 0, stream>>>(x, hxs, hys, gru_init, masks, at,
                                          w_ih, w_hh, w_ih_p, w_hh_p,
                                          x2, W2, whh, whhp, hbuf, flags);
    gi_gemm<<<3072, 256, 0, stream>>>(x2, W2, GI);

    const int ldsBytes = 48*520*2 + 64*520*2 + 48*8*4 + 64*8*4;   // 120,064
    (void)hipFuncSetAttribute((const void*)recurrent_kernel,
                              hipFuncAttributeMaxDynamicSharedMemorySize, ldsBytes);
    recurrent_kernel<<<256, 256, ldsBytes, stream>>>(out, GI, whh, whhp, hbuf, flags,
                                                     masks, gru_init, at, w_ih_p,
                                                     b_ih, b_hh, b_ih_p, b_hh_p);
}

// Round 4
// 1213.997 us; speedup vs baseline: 1.6530x; 1.6530x over previous
//
#include <hip/hip_runtime.h>
#include <hip/hip_bf16.h>
#include <stdint.h>

typedef unsigned short ushort_t;
typedef __attribute__((ext_vector_type(8))) short bf16x8;
typedef __attribute__((ext_vector_type(4))) float f32x4;

#define T_DIM 128
#define N_DIM 256
#define H_DIM 512
#define G3    1536
#define K2DIM 544   // 520 padded to multiple of 32

#define SCOPE_SYS __HIP_MEMORY_SCOPE_SYSTEM

// ---- ws layout (bytes) ----
#define OFF_X2    0L
#define SZ_X2     (32768L*K2DIM*2)
#define OFF_W2    (OFF_X2 + SZ_X2)
#define SZ_W2     (1536L*K2DIM*2)
#define OFF_WHH   (OFF_W2 + SZ_W2)
#define SZ_WHH    (1536L*512*2)
#define OFF_WHHP  (OFF_WHH + SZ_WHH)
#define OFF_GI    (OFF_WHHP + SZ_WHH)
#define SZ_GI     (32768L*1536*2)
#define OFF_HBUF  (OFF_GI + SZ_GI)
#define SZ_HBUF   (4L*N_DIM*H_DIM*2)                     // [cell][parity][n*512+k]
#define OFF_FLAGS (OFF_HBUF + SZ_HBUF)
#define SZ_FLAGS  (8L*128*4)

// output offsets (floats)
#define OUT_OUTS   0L
#define OUT_HXS    16777216L
#define OUT_OUTSP  16908288L
#define OUT_HYS    33685504L

__device__ __forceinline__ ushort_t f2bf(float f) {
    union { float f; unsigned u; } v; v.f = f;
    unsigned u = v.u;
    u += 0x7fffu + ((u >> 16) & 1u);   // RNE
    return (ushort_t)(u >> 16);
}
__device__ __forceinline__ float bf2f(unsigned u) {
    union { unsigned u; float f; } v; v.u = u << 16;
    return v.f;
}
__device__ __forceinline__ float sigm(float x) { return 1.f / (1.f + __expf(-x)); }

// system-scope relaxed (sc0 sc1: bypass L1+L2, no wbl2/inv fences)
__device__ __forceinline__ unsigned long long ld64_sys(const void* p) {
    return __hip_atomic_load((const unsigned long long*)p, __ATOMIC_RELAXED, SCOPE_SYS);
}
__device__ __forceinline__ ushort_t ld16_sys(const ushort_t* p) {
    return __hip_atomic_load(p, __ATOMIC_RELAXED, SCOPE_SYS);
}
__device__ __forceinline__ void st16_sys(ushort_t* p, ushort_t v) {
    __hip_atomic_store(p, v, __ATOMIC_RELAXED, SCOPE_SYS);
}

// ============================ K1: prep ============================
__global__ __launch_bounds__(256) void prep_kernel(
    const float* __restrict__ x, const float* __restrict__ hxs, const float* __restrict__ hys,
    const float* __restrict__ gru_init, const float* __restrict__ masks, const float* __restrict__ at,
    const float* __restrict__ w_ih, const float* __restrict__ w_hh,
    const float* __restrict__ w_ih_p, const float* __restrict__ w_hh_p,
    ushort_t* __restrict__ x2, ushort_t* __restrict__ W2,
    ushort_t* __restrict__ whh, ushort_t* __restrict__ whhp,
    ushort_t* __restrict__ hbuf, int* __restrict__ flags)
{
    const long n_x2   = 32768L * K2DIM;
    const long n_W2   = 1536L * K2DIM;
    const long n_whh  = 1536L * 512;
    const long n_h    = 256L * 512;
    const long total  = n_x2 + n_W2 + 2*n_whh + 2*n_h + 8*128;
    for (long i = (long)blockIdx.x * blockDim.x + threadIdx.x; i < total;
         i += (long)gridDim.x * blockDim.x) {
        long j = i;
        if (j < n_x2) {   // x2 = [x | at*mask | 0pad] bf16
            int r = (int)(j / K2DIM), c = (int)(j % K2DIM);
            float v;
            if (c < 512)       v = x[(long)r*512 + c];
            else if (c < 520)  v = at[(long)r*8 + (c - 512)] * masks[r];
            else               v = 0.f;
            x2[j] = f2bf(v); continue;
        }
        j -= n_x2;
        if (j < n_W2) {   // W2 = w_ih padded to 544 cols
            int r = (int)(j / K2DIM), c = (int)(j % K2DIM);
            W2[j] = f2bf(c < 520 ? w_ih[(long)r*520 + c] : 0.f); continue;
        }
        j -= n_W2;
        if (j < n_whh) { whh[j]  = f2bf(w_hh[j]);   continue; }
        j -= n_whh;
        if (j < n_whh) { whhp[j] = f2bf(w_hh_p[j]); continue; }
        j -= n_whh;
        if (j < n_h) {    // hbuf cell0 parity0: hxs * m0
            int n = (int)(j >> 9); float m = masks[n];
            hbuf[j] = f2bf(hxs[j] * m); continue;
        }
        j -= n_h;
        if (j < n_h) {    // hbuf cell1 parity0: hys*m0 + g0*(1-m0)
            int n = (int)(j >> 9); float m = masks[n];
            hbuf[2*131072 + j] = f2bf(hys[j] * m + gru_init[j] * (1.f - m)); continue;
        }
        j -= n_h;
        flags[j] = 0;
    }
}

// ============================ K2: GI GEMM ============================
// GI(32768 x 1536) bf16 = x2(32768 x 544) @ W2(1536 x 544)^T   (no bias)
__global__ __launch_bounds__(256) void gi_gemm(
    const ushort_t* __restrict__ x2, const ushort_t* __restrict__ W2, ushort_t* __restrict__ GI)
{
    __shared__ ushort_t As2[128 * 40];
    __shared__ ushort_t Bs2[128 * 40];
    const int bid = blockIdx.x;
    const int m0 = (bid & 255) * 128;
    const int j0 = (bid >> 8) * 128;
    const int w = threadIdx.x >> 6, l = threadIdx.x & 63;
    const int lrow = l & 15, lq = l >> 4;
    const int wm = (w & 1) * 64, wn = (w >> 1) * 64;
    const int srow = threadIdx.x >> 1, shalf = threadIdx.x & 1;

    f32x4 acc[4][4] = {};
    for (int k0 = 0; k0 < K2DIM; k0 += 32) {
        __syncthreads();
        {
            const ushort_t* sa = x2 + (long)(m0 + srow) * K2DIM + k0 + shalf * 16;
            *(uint4*)(As2 + srow*40 + shalf*16)     = *(const uint4*)(sa);
            *(uint4*)(As2 + srow*40 + shalf*16 + 8) = *(const uint4*)(sa + 8);
            const ushort_t* sb = W2 + (long)(j0 + srow) * K2DIM + k0 + shalf * 16;
            *(uint4*)(Bs2 + srow*40 + shalf*16)     = *(const uint4*)(sb);
            *(uint4*)(Bs2 + srow*40 + shalf*16 + 8) = *(const uint4*)(sb + 8);
        }
        __syncthreads();
        bf16x8 a[4], b[4];
#pragma unroll
        for (int i = 0; i < 4; ++i) a[i] = *(const bf16x8*)(As2 + (wm + i*16 + lrow)*40 + lq*8);
#pragma unroll
        for (int jj = 0; jj < 4; ++jj) b[jj] = *(const bf16x8*)(Bs2 + (wn + jj*16 + lrow)*40 + lq*8);
#pragma unroll
        for (int i = 0; i < 4; ++i)
#pragma unroll
            for (int jj = 0; jj < 4; ++jj)
                acc[i][jj] = __builtin_amdgcn_mfma_f32_16x16x32_bf16(a[i], b[jj], acc[i][jj], 0, 0, 0);
    }
#pragma unroll
    for (int i = 0; i < 4; ++i) {
        int mrow_b = m0 + wm + i*16 + lq*4;
#pragma unroll
        for (int jj = 0; jj < 4; ++jj) {
            int coln = j0 + wn + jj*16 + lrow;
#pragma unroll
            for (int reg = 0; reg < 4; ++reg)
                GI[(long)(mrow_b + reg) * G3 + coln] = f2bf(acc[i][jj][reg]);
        }
    }
}

// ============================ K3: persistent recurrent (fence-free) ============================
// 256 blocks x 256 threads, 1 block/CU. Block: cell x rowgroup(64 rows) x colgroup(16 h-cols).
// Group = blockIdx&7 -> 32 col-blocks; h exchange via system-scope relaxed atomics
// (sc0 sc1 write-through/bypass loads, NO wbl2/inv fences); flags via relaxed
// system atomicAdd + throttled bounded poll.
__global__ __launch_bounds__(256, 1) void recurrent_kernel(
    float* __restrict__ d_out,
    const ushort_t* __restrict__ GI,
    const ushort_t* __restrict__ whh, const ushort_t* __restrict__ whhp,
    ushort_t* __restrict__ hbuf, int* __restrict__ flags,
    const float* __restrict__ masks, const float* __restrict__ gru_init,
    const float* __restrict__ at, const float* __restrict__ w_ih_p,
    const float* __restrict__ b_ih, const float* __restrict__ b_hh,
    const float* __restrict__ b_ih_p, const float* __restrict__ b_hh_p)
{
    const int bid = blockIdx.x;
    const int g    = bid & 7;
    const int cell = g & 1;
    const int rg   = g >> 1;
    const int cg   = bid >> 3;
    const int rows0 = rg * 64;
    const int hcol0 = cg * 16;
    const int tid = threadIdx.x;
    const int w = tid >> 6, l = tid & 63;
    const int lrow = l & 15, lq = l >> 4;
    const int col = hcol0 + lrow;
    const int nbase = rows0 + w * 16 + lq * 4;      // first of this lane's 4 C rows

    // ---- hoist all 48 B-fragments (step-invariant) into registers ----
    const ushort_t* Wg = cell ? whhp : whh;
    bf16x8 bw[3][16];
#pragma unroll
    for (int gate = 0; gate < 3; ++gate) {
        const ushort_t* base = Wg + ((long)(gate * 512 + col)) * 512 + lq * 8;
#pragma unroll
        for (int ks = 0; ks < 16; ++ks)
            bw[gate][ks] = *(const bf16x8*)(base + ks * 32);
    }
    // cell1: hoist action-weight rows (w_ih_p is 1536 x 8, row = gate*512 + col)
    float war[8], waz[8], wan[8];
    if (cell) {
#pragma unroll
        for (int k = 0; k < 8; ++k) {
            war[k] = w_ih_p[((long)col) * 8 + k];
            waz[k] = w_ih_p[((long)(512 + col)) * 8 + k];
            wan[k] = w_ih_p[((long)(1024 + col)) * 8 + k];
        }
    }
    // per-lane biases
    const float* bi = cell ? b_ih_p : b_ih;
    const float* bh = cell ? b_hh_p : b_hh;
    const float bihr = bi[col], bihz = bi[512 + col], bihn = bi[1024 + col];
    const float bhhr = bh[col], bhhz = bh[512 + col], bhhn = bh[1024 + col];

#pragma unroll 1
    for (int t = 0; t < T_DIM; ++t) {
        // ---- prefetch (independent of the flag) so latency hides behind the wait ----
        unsigned giu[12];
        float atv[4][8], m_t[4], m_t1[4], gini[4];
        if (cell == 0) {
#pragma unroll
            for (int reg = 0; reg < 4; ++reg) {
                const ushort_t* gi = GI + ((long)t * 256 + nbase + reg) * G3;
                giu[reg * 3 + 0] = gi[col];
                giu[reg * 3 + 1] = gi[512 + col];
                giu[reg * 3 + 2] = gi[1024 + col];
            }
        } else {
#pragma unroll
            for (int reg = 0; reg < 4; ++reg) {
                const float* ap = at + ((long)t * 256 + nbase + reg) * 8;
                float4 a0 = *(const float4*)(ap);
                float4 a1 = *(const float4*)(ap + 4);
                atv[reg][0] = a0.x; atv[reg][1] = a0.y; atv[reg][2] = a0.z; atv[reg][3] = a0.w;
                atv[reg][4] = a1.x; atv[reg][5] = a1.y; atv[reg][6] = a1.z; atv[reg][7] = a1.w;
                m_t[reg] = masks[t * 256 + nbase + reg];
            }
        }
#pragma unroll
        for (int reg = 0; reg < 4; ++reg) {
            if (t < T_DIM - 1) {
                m_t1[reg] = masks[(t + 1) * 256 + nbase + reg];
                gini[reg] = cell ? gru_init[((long)(t + 1) * 256 + nbase + reg) * 512 + col] : 0.f;
            } else { m_t1[reg] = 0.f; gini[reg] = 0.f; }
        }

        // ---- wait for step-t h (written by step t-1 producers of this group) ----
        if (t > 0) {
            if (tid == 0) {
                int* fl = &flags[g * 128 + t];
                int spins = 0;
                while (__hip_atomic_load(fl, __ATOMIC_RELAXED, SCOPE_SYS) < 32) {
                    if (++spins > (1 << 16)) break;   // fail loud (finite wrong result), never hang
                    __builtin_amdgcn_s_sleep(2);      // throttle: don't hammer the flag line
                }
            }
            __syncthreads();
        }

        // ---- A fragments + htil: direct global->register, system-scope (bypass caches) ----
        const ushort_t* hsrc = hbuf + ((cell * 2 + (t & 1)) * 131072);
        const ushort_t* pa = hsrc + ((rows0 + w * 16 + lrow) << 9) + lq * 8;
        bf16x8 afrag[16];
#pragma unroll
        for (int ks = 0; ks < 16; ++ks) {
            union { unsigned long long q[2]; bf16x8 v; } u;
            u.q[0] = ld64_sys(pa + ks * 32);
            u.q[1] = ld64_sys(pa + ks * 32 + 4);
            afrag[ks] = u.v;
        }
        const ushort_t* ph = hsrc + ((long)nbase << 9) + col;
        unsigned htu[4];
#pragma unroll
        for (int reg = 0; reg < 4; ++reg) htu[reg] = ld16_sys(ph + (reg << 9));

        // ---- MFMA: 16 rows x 48 gate-cols per wave, K=512 ----
        f32x4 accR = {0.f,0.f,0.f,0.f}, accZ = {0.f,0.f,0.f,0.f}, accN = {0.f,0.f,0.f,0.f};
#pragma unroll
        for (int ks = 0; ks < 16; ++ks) {
            accR = __builtin_amdgcn_mfma_f32_16x16x32_bf16(afrag[ks], bw[0][ks], accR, 0, 0, 0);
            accZ = __builtin_amdgcn_mfma_f32_16x16x32_bf16(afrag[ks], bw[1][ks], accZ, 0, 0, 0);
            accN = __builtin_amdgcn_mfma_f32_16x16x32_bf16(afrag[ks], bw[2][ks], accN, 0, 0, 0);
        }

        // ---- epilogue: gate math + stores ----
        float* outBase = d_out + (cell ? OUT_OUTSP : OUT_OUTS);
        ushort_t* hnext = hbuf + ((cell * 2 + ((t + 1) & 1)) * 131072);
#pragma unroll
        for (int reg = 0; reg < 4; ++reg) {
            int nabs = nbase + reg;
            long row_tn = (long)t * 256 + nabs;
            float gir, giz, gin;
            if (cell == 0) {
                gir = bf2f(giu[reg * 3 + 0]);
                giz = bf2f(giu[reg * 3 + 1]);
                gin = bf2f(giu[reg * 3 + 2]);
            } else {
                gir = 0.f; giz = 0.f; gin = 0.f;
                float m = m_t[reg];
#pragma unroll
                for (int k = 0; k < 8; ++k) {
                    float ma = atv[reg][k] * m;
                    gir += ma * war[k]; giz += ma * waz[k]; gin += ma * wan[k];
                }
            }
            float r = sigm(gir + bihr + accR[reg] + bhhr);
            float z = sigm(giz + bihz + accZ[reg] + bhhz);
            float n = tanhf(gin + bihn + r * (accN[reg] + bhhn));
            float htil = bf2f((unsigned)htu[reg]);
            float hnew = (1.f - z) * n + z * htil;

            outBase[row_tn * 512 + col] = hnew;
            if (t == T_DIM - 1) {
                float* fin = d_out + (cell ? OUT_HYS : OUT_HXS);
                fin[(long)nabs * 512 + col] = hnew;
            } else {
                float mn = m_t1[reg];
                float hn = cell ? (hnew * mn + gini[reg] * (1.f - mn)) : (hnew * mn);
                st16_sys(hnext + ((long)nabs << 9) + col, f2bf(hn));
            }
        }
        // __syncthreads() emits a full s_waitcnt vmcnt(0) drain before s_barrier,
        // so all system-scope h stores of this block are at the coherence point
        // before tid 0 publishes the flag.
        __syncthreads();
        if (t < T_DIM - 1 && tid == 0)
            __hip_atomic_fetch_add(&flags[g * 128 + (t + 1)], 1,
                                   __ATOMIC_RELAXED, SCOPE_SYS);
    }
}

// ============================ launcher ============================
extern "C" void kernel_launch(void* const* d_in, const int* in_sizes, int n_in,
                              void* d_out, int out_size, void* d_ws, size_t ws_size,
                              hipStream_t stream) {
    const float* x        = (const float*)d_in[0];
    const float* hxs      = (const float*)d_in[1];
    const float* hys      = (const float*)d_in[2];
    const float* gru_init = (const float*)d_in[3];
    const float* masks    = (const float*)d_in[4];
    const float* at       = (const float*)d_in[5];
    const float* w_ih     = (const float*)d_in[6];
    const float* w_hh     = (const float*)d_in[7];
    const float* b_ih     = (const float*)d_in[8];
    const float* b_hh     = (const float*)d_in[9];
    const float* w_ih_p   = (const float*)d_in[10];
    const float* w_hh_p   = (const float*)d_in[11];
    const float* b_ih_p   = (const float*)d_in[12];
    const float* b_hh_p   = (const float*)d_in[13];
    float* out = (float*)d_out;

    char* ws = (char*)d_ws;
    ushort_t* x2    = (ushort_t*)(ws + OFF_X2);
    ushort_t* W2    = (ushort_t*)(ws + OFF_W2);
    ushort_t* whh   = (ushort_t*)(ws + OFF_WHH);
    ushort_t* whhp  = (ushort_t*)(ws + OFF_WHHP);
    ushort_t* GI    = (ushort_t*)(ws + OFF_GI);
    ushort_t* hbuf  = (ushort_t*)(ws + OFF_HBUF);
    int*      flags = (int*)(ws + OFF_FLAGS);

    prep_kernel<<<2048, 256, 0, stream>>>(x, hxs, hys, gru_init, masks, at,
                                          w_ih, w_hh, w_ih_p, w_hh_p,
                                          x2, W2, whh, whhp, hbuf, flags);
    gi_gemm<<<3072, 256, 0, stream>>>(x2, W2, GI);
    recurrent_kernel<<<256, 256, 0, stream>>>(out, GI, whh, whhp, hbuf, flags,
                                              masks, gru_init, at, w_ih_p,
                                              b_ih, b_hh, b_ih_p, b_hh_p);
}